// Round 2
// baseline (249.601 us; speedup 1.0000x reference)
//
#include <hip/hip_runtime.h>
#include <math.h>

#define B_  2
#define N_  50
#define n_  15
#define C_  17
#define HW_ 4096
#define KC  64
#define KOUT 4
#define NKG (HW_/(KC*KOUT))   // 16 k-groups
#define PSTR 52               // pred feature LDS row stride (floats); b128 reads 2-way bank alias (free)
#define GSTR 20               // gt feature LDS row stride (floats); b128 reads conflict-free

// ws layout (floats): [0,510) notmask (1.0 = has keypoints, 0.0 = masked)
//                     [512,542) num_kp per (b,j)

// ---------------- kernel 1: per-(b,j,c) all-zero mask ----------------
__global__ void mask_kernel(const float* __restrict__ gh, float* __restrict__ ws) {
    int c = blockIdx.x, j = blockIdx.y, b = blockIdx.z;
    const float* row = gh + (((size_t)(b * n_ + j)) * C_ + c) * HW_;
    int tid = threadIdx.x;
    int any = 0;
    for (int e = 0; e < 4; ++e) {
        float4 v = *(const float4*)(row + (size_t)e * 1024 + tid * 4);
        any |= (v.x != 0.f) | (v.y != 0.f) | (v.z != 0.f) | (v.w != 0.f);
    }
    __shared__ int s_any;
    if (tid == 0) s_any = 0;
    __syncthreads();
    if (any) atomicOr(&s_any, 1);
    __syncthreads();
    if (tid == 0) ws[(b * n_ + j) * C_ + c] = s_any ? 1.f : 0.f;
}

// ---------------- kernel 2: num_kp per (b,j) ----------------
__global__ void numkp_kernel(float* __restrict__ ws) {
    int t = threadIdx.x;
    if (t < B_ * n_) {
        float cnt = 0.f;
        for (int c = 0; c < C_; ++c) cnt += ws[t * C_ + c];
        ws[512 + t] = fmaxf(cnt, 1.f);
    }
}

// ---------------- kernel 3: score + offset cost, plain store ----------------
__global__ void scoreoff_kernel(const float* __restrict__ ps, const float* __restrict__ po,
                                const float* __restrict__ go, const float* __restrict__ ws,
                                float* __restrict__ out) {
    int idx = blockIdx.x * 256 + threadIdx.x;
    if (idx >= B_ * N_ * n_) return;
    int b = idx / (N_ * n_);
    int rem = idx % (N_ * n_);
    int i = rem / n_, j = rem % n_;

    float s  = ps[b * N_ + i];
    float e  = expf(-fabsf(s));
    float spn = fmaxf(-s, 0.f) + log1pf(e);      // softplus(-s)
    float r  = 1.f / (1.f + e);
    float sig = (s >= 0.f) ? r : e * r;          // sigmoid(s)
    float om = 1.f - sig;
    float sc = 0.25f * spn * om * om;            // ALPHA * softplus(-s) * (1-sig)^2

    float off = 0.f;
    const float* nmrow = ws + (b * n_ + j) * C_;
    for (int c = 0; c < C_; ++c) {
        float nm = nmrow[c];
        if (nm != 0.f) {
            for (int d = 0; d < 2; ++d) {
                float x = po[((b * N_ + i) * C_ + c) * 2 + d];
                float g = go[((b * n_ + j) * C_ + c) * 2 + d];
                float ee = expf(-fabsf(x));
                float rr = 1.f / (1.f + ee);
                float sg = (x >= 0.f) ? rr : ee * rr;
                float dd = sg - g;
                off += dd * dd;
            }
        }
    }
    out[idx] = sc + off / ws[512 + b * n_ + j] * 0.5f;
}

// ---------------- kernel 4: hm cost as feature GEMM ----------------
#define FMA4(acc, a, u) \
    acc.x = fmaf(a, u.x, acc.x); acc.y = fmaf(a, u.y, acc.y); \
    acc.z = fmaf(a, u.z, acc.z); acc.w = fmaf(a, u.w, acc.w);

__global__ __launch_bounds__(256) void hm_kernel(const float* __restrict__ ph,
                                                 const float* __restrict__ gh,
                                                 const float* __restrict__ ws,
                                                 float* __restrict__ out) {
    __shared__ __align__(16) float sA1[KC * PSTR];
    __shared__ __align__(16) float sA2[KC * PSTR];
    __shared__ __align__(16) float sB1[KC * PSTR];
    __shared__ __align__(16) float sU [KC * GSTR];
    __shared__ __align__(16) float sV [KC * GSTR];
    __shared__ __align__(16) float sW [KC * GSTR];

    int kg = blockIdx.x, c = blockIdx.y, b = blockIdx.z;
    int tid = threadIdx.x;
    int w = tid >> 6, lane = tid & 63;

    // hoisted gt-side scale per j-quad (wave w owns j-quad w)
    float g_scale[4];
    for (int s = 0; s < 4; ++s) {
        int j = 4 * w + s;
        g_scale[s] = (j < n_) ? ws[(b * n_ + j) * C_ + c] * 2.f / ws[512 + b * n_ + j] : 0.f;
    }

    int it = lane % 13, jt = lane / 13;
    bool active = lane < 52;
    float4 acc0 = make_float4(0.f, 0.f, 0.f, 0.f);
    float4 acc1 = acc0, acc2 = acc0, acc3 = acc0;

    for (int t_out = 0; t_out < KOUT; ++t_out) {
        int k0 = (kg * KOUT + t_out) * KC;

        // ---- stage gt features: wave w owns j-quad w; lane = k ----
        {
            int kk = lane;
            float uq[4], vq[4], wq[4];
            for (int s = 0; s < 4; ++s) {
                int j = 4 * w + s;
                float t = 0.f;
                if (j < n_)
                    t = gh[(((size_t)(b * n_ + j)) * C_ + c) * HW_ + k0 + kk];
                float scale = g_scale[s];
                float q = 1.f - t, q2 = q * q, u = q2 * q2;
                uq[s] = u * scale;
                vq[s] = t * u * scale;
                wq[s] = (t == 1.f) ? scale : 0.f;
            }
            *(float4*)&sU[kk * GSTR + 4 * w] = make_float4(uq[0], uq[1], uq[2], uq[3]);
            *(float4*)&sV[kk * GSTR + 4 * w] = make_float4(vq[0], vq[1], vq[2], vq[3]);
            *(float4*)&sW[kk * GSTR + 4 * w] = make_float4(wq[0], wq[1], wq[2], wq[3]);
        }
        // ---- stage pred features: wave w owns i-quads {w, w+4, w+8, w+12} ----
        {
            int kk = lane;
            for (int q = w; q < 13; q += 4) {
                float a1[4], a2[4], b1[4];
                for (int s = 0; s < 4; ++s) {
                    int i = 4 * q + s;
                    float x = (i < N_) ? ph[(((size_t)(b * N_ + i)) * C_ + c) * HW_ + k0 + kk] : 0.f;
                    float e  = expf(-fabsf(x));
                    float sp = fmaxf(x, 0.f) + log1pf(e);   // softplus(x)
                    float r  = 1.f / (1.f + e);
                    float p  = (x >= 0.f) ? r : e * r;      // sigmoid(x)
                    float p2 = p * p;
                    a1[s] = sp * p2;
                    a2[s] = -x * p2;
                    float om = 1.f - p;
                    b1[s] = (sp - x) * om * om;
                }
                *(float4*)&sA1[kk * PSTR + 4 * q] = make_float4(a1[0], a1[1], a1[2], a1[3]);
                *(float4*)&sA2[kk * PSTR + 4 * q] = make_float4(a2[0], a2[1], a2[2], a2[3]);
                *(float4*)&sB1[kk * PSTR + 4 * q] = make_float4(b1[0], b1[1], b1[2], b1[3]);
            }
        }
        __syncthreads();

        // ---- contraction: wave w covers k in [16w, 16w+16); thread tile 4i x 4j ----
        if (active) {
#pragma unroll 4
            for (int kk = 0; kk < 16; ++kk) {
                int k = w * 16 + kk;
                float4 a1 = *(const float4*)&sA1[k * PSTR + 4 * it];
                float4 a2 = *(const float4*)&sA2[k * PSTR + 4 * it];
                float4 b1 = *(const float4*)&sB1[k * PSTR + 4 * it];
                float4 u4 = *(const float4*)&sU[k * GSTR + 4 * jt];
                float4 v4 = *(const float4*)&sV[k * GSTR + 4 * jt];
                float4 w4 = *(const float4*)&sW[k * GSTR + 4 * jt];
                FMA4(acc0, a1.x, u4) FMA4(acc0, a2.x, v4) FMA4(acc0, b1.x, w4)
                FMA4(acc1, a1.y, u4) FMA4(acc1, a2.y, v4) FMA4(acc1, b1.y, w4)
                FMA4(acc2, a1.z, u4) FMA4(acc2, a2.z, v4) FMA4(acc2, b1.z, w4)
                FMA4(acc3, a1.w, u4) FMA4(acc3, a2.w, v4) FMA4(acc3, b1.w, w4)
            }
        }
        __syncthreads();   // LDS consumed; safe to restage next iteration
    }

    // ---- cross-wave reduce in LDS (reuse sA1 region; rows of 20 floats) ----
    float* scratch = sA1;
    if (w > 0 && active) {
        float* dst = scratch + ((w - 1) * 52 + lane) * 20;
        *(float4*)(dst + 0)  = acc0;
        *(float4*)(dst + 4)  = acc1;
        *(float4*)(dst + 8)  = acc2;
        *(float4*)(dst + 12) = acc3;
    }
    __syncthreads();
    if (w == 0 && active) {
        for (int r = 0; r < 3; ++r) {
            const float* src = scratch + (r * 52 + lane) * 20;
            float4 t0 = *(const float4*)(src + 0);
            float4 t1 = *(const float4*)(src + 4);
            float4 t2 = *(const float4*)(src + 8);
            float4 t3 = *(const float4*)(src + 12);
            acc0.x += t0.x; acc0.y += t0.y; acc0.z += t0.z; acc0.w += t0.w;
            acc1.x += t1.x; acc1.y += t1.y; acc1.z += t1.z; acc1.w += t1.w;
            acc2.x += t2.x; acc2.y += t2.y; acc2.z += t2.z; acc2.w += t2.w;
            acc3.x += t3.x; acc3.y += t3.y; acc3.z += t3.z; acc3.w += t3.w;
        }
        float4 accs[4] = {acc0, acc1, acc2, acc3};
        for (int s = 0; s < 4; ++s) {
            int i = 4 * it + s;
            if (i < N_) {
                float vals[4] = {accs[s].x, accs[s].y, accs[s].z, accs[s].w};
                for (int cmp = 0; cmp < 4; ++cmp) {
                    int j = 4 * jt + cmp;
                    if (j < n_) atomicAdd(&out[(size_t)(b * N_ + i) * n_ + j], vals[cmp]);
                }
            }
        }
    }
}

extern "C" void kernel_launch(void* const* d_in, const int* in_sizes, int n_in,
                              void* d_out, int out_size, void* d_ws, size_t ws_size,
                              hipStream_t stream) {
    const float* ph = (const float*)d_in[0];   // pred_hms      [B,N,C,H,W]
    const float* ps = (const float*)d_in[1];   // pred_scores   [B,N,1]
    const float* po = (const float*)d_in[2];   // pred_offsets  [B,N,C,2]
    const float* gh = (const float*)d_in[3];   // gt_heatmaps   [B,n,C,H,W]
    const float* go = (const float*)d_in[4];   // gt_offsets    [B,n,C,2]
    float* out = (float*)d_out;
    float* ws  = (float*)d_ws;

    mask_kernel<<<dim3(C_, n_, B_), 256, 0, stream>>>(gh, ws);
    numkp_kernel<<<1, 64, 0, stream>>>(ws);
    scoreoff_kernel<<<(B_ * N_ * n_ + 255) / 256, 256, 0, stream>>>(ps, po, go, ws, out);
    hm_kernel<<<dim3(NKG, C_, B_), 256, 0, stream>>>(ph, gh, ws, out);
}